// Round 1
// baseline (331.129 us; speedup 1.0000x reference)
//
#include <hip/hip_runtime.h>
#include <math.h>

#define B_ 8
#define N_ 2048
#define NT_ (B_*N_)          // 16384 rows
#define OUTSZ (NT_*64)       // 1048576 elements per output tensor

// ---- workspace layout (float offsets). Wh lives in d_out[0:OUTSZ] (dead until k5 overwrites).
#define WS_XH    0
#define WS_ASRC  (WS_XH + NT_*64)       // 1048576
#define WS_ADST  (WS_ASRC + NT_)
#define WS_GMAX  (WS_ADST + NT_)
#define WS_WT    (WS_GMAX + 32)         // [128][256] fused gate weights (transposed)
#define WS_BB    (WS_WT + 128*256)      // [256] combined gate bias
#define WS_WOT   (WS_BB + 256)          // [128][64] Wout transposed
// total = 1,122,592 floats ~= 4.5 MB

__device__ __forceinline__ float lrelu2(float x) { return x > 0.f ? x : 2.f * x; }
__device__ __forceinline__ float f4get(const float4& v, int k) { return k==0?v.x:(k==1?v.y:(k==2?v.z:v.w)); }

// ---------------- K0: weight prep (transpose gate weights into [k][256], WoutT) ----------------
__global__ void k0_prep(const float* Wf, const float* Wi, const float* Wo, const float* Wc,
                        const float* Uf, const float* Ui, const float* Uo, const float* Uc,
                        const float* bWf, const float* bWi, const float* bWo, const float* bWc,
                        const float* bUf, const float* bUi, const float* bUo, const float* bUc,
                        const float* Wout, float* ws)
{
    int idx = blockIdx.x * 256 + threadIdx.x;
    if (idx < 128 * 256) {
        int k = idx >> 8, o = idx & 255;
        int g = o >> 6, u = o & 63;
        const float* Wg = (g == 0) ? Wf : (g == 1) ? Wi : (g == 2) ? Wo : Wc;
        const float* Ug = (g == 0) ? Uf : (g == 1) ? Ui : (g == 2) ? Uo : Uc;
        ws[WS_WT + idx] = (k < 64) ? Wg[u * 64 + k] : Ug[u * 64 + (k - 64)];
    } else if (idx < 128 * 256 + 256) {
        int o = idx - 128 * 256;
        int g = o >> 6, u = o & 63;
        const float* bW = (g == 0) ? bWf : (g == 1) ? bWi : (g == 2) ? bWo : bWc;
        const float* bU = (g == 0) ? bUf : (g == 1) ? bUi : (g == 2) ? bUo : bUc;
        ws[WS_BB + o] = bW[u] + bU[u];
    } else if (idx < 128 * 256 + 256 + 128 * 64) {
        int j = idx - (128 * 256 + 256);
        int k = j >> 6, u = j & 63;
        ws[WS_WOT + j] = Wout[u * 128 + k];   // WoutT[k][u]
    }
}

// ---------------- K1: Wh = x@W, a_src, a_dst.  64 rows/block, 4x4 reg tile ----------------
__global__ __launch_bounds__(256) void k1_wh(const float* __restrict__ x, const float* __restrict__ W,
                                             const float* __restrict__ a, float* __restrict__ ws,
                                             float* __restrict__ wh)
{
    __shared__ float xl[64 * 68];
    __shared__ float Wl[64 * 68];
    int t = threadIdx.x;
    int i0 = blockIdx.x * 64;
    #pragma unroll
    for (int it = 0; it < 4; ++it) {
        int f = t + 256 * it;
        int r = f >> 4, q = f & 15;
        *(float4*)&xl[r * 68 + q * 4] = *(const float4*)&x[i0 * 64 + f * 4];
        *(float4*)&Wl[r * 68 + q * 4] = *(const float4*)&W[f * 4];
    }
    __syncthreads();
    int cg = t & 15, rg = t >> 4;
    int c0 = cg * 4, r0 = rg * 4;
    float acc[4][4] = {};
    #pragma unroll
    for (int d0 = 0; d0 < 64; d0 += 4) {
        float4 wv[4], xv[4];
        #pragma unroll
        for (int k = 0; k < 4; ++k) wv[k] = *(float4*)&Wl[(d0 + k) * 68 + c0];
        #pragma unroll
        for (int ri = 0; ri < 4; ++ri) xv[ri] = *(float4*)&xl[(r0 + ri) * 68 + d0];
        #pragma unroll
        for (int ri = 0; ri < 4; ++ri)
            #pragma unroll
            for (int k = 0; k < 4; ++k) {
                float xs = f4get(xv[ri], k);
                acc[ri][0] += xs * wv[k].x; acc[ri][1] += xs * wv[k].y;
                acc[ri][2] += xs * wv[k].z; acc[ri][3] += xs * wv[k].w;
            }
    }
    float4 a0 = *(const float4*)&a[c0];
    float4 a1 = *(const float4*)&a[64 + c0];
    #pragma unroll
    for (int ri = 0; ri < 4; ++ri) {
        int row = i0 + r0 + ri;
        *(float4*)&wh[row * 64 + c0] = make_float4(acc[ri][0], acc[ri][1], acc[ri][2], acc[ri][3]);
        float s0 = acc[ri][0]*a0.x + acc[ri][1]*a0.y + acc[ri][2]*a0.z + acc[ri][3]*a0.w;
        float s1 = acc[ri][0]*a1.x + acc[ri][1]*a1.y + acc[ri][2]*a1.z + acc[ri][3]*a1.w;
        #pragma unroll
        for (int m = 1; m < 16; m <<= 1) { s0 += __shfl_xor(s0, m, 64); s1 += __shfl_xor(s1, m, 64); }
        if (cg == 0) { ws[WS_ASRC + row] = s0; ws[WS_ADST + row] = s1; }
    }
}

// ---------------- K1b: per-batch max of a_dst ----------------
__global__ void k1b_gmax(float* ws)
{
    __shared__ float red[256];
    int b = blockIdx.x, t = threadIdx.x;
    float m = -3.0e38f;
    for (int j = t; j < N_; j += 256) m = fmaxf(m, ws[WS_ADST + b * N_ + j]);
    red[t] = m; __syncthreads();
    for (int s = 128; s > 0; s >>= 1) { if (t < s) red[t] = fmaxf(red[t], red[t + s]); __syncthreads(); }
    if (t == 0) ws[WS_GMAX + b] = red[0];
}

// ---------------- K2: masked softmax-weighted GEMM (x_hidden) ----------------
// 64 rows/block, 64-j chunks. p = adj>0 ? exp(LR(asrc+adst)-M) : 0 with M a valid global shift
// (leakyrelu slope 2 is monotonic => M = LR(asrc+max_j adst) >= row max). Denominator folded
// into GEMM phase (redundant per-thread dpart sums -> no cross-lane traffic).
__global__ __launch_bounds__(256) void k2_att(const float* __restrict__ adj, const float* __restrict__ wh,
                                              float* __restrict__ ws)
{
    __shared__ float Whl[64 * 68];
    __shared__ float pl[64 * 68];
    __shared__ float asl[64], Ml[64];
    int t = threadIdx.x;
    int blk = blockIdx.x;
    int b = blk >> 5;            // 32 blocks per batch
    int i0 = (blk & 31) << 6;
    int bN = b * N_;
    if (t < 64) {
        float as = ws[WS_ASRC + bN + i0 + t];
        asl[t] = as;
        Ml[t] = lrelu2(as + ws[WS_GMAX + b]);
    }
    __syncthreads();
    int cg = t & 15, rgG = t >> 4;
    int c0 = cg * 4, r0 = rgG * 4;
    int w = t >> 6, jl = t & 63;
    float acc[4][4] = {};
    float dpart[4] = {};
    for (int j0 = 0; j0 < N_; j0 += 64) {
        // stage Wh tile [64 j][64 h]
        #pragma unroll
        for (int it = 0; it < 4; ++it) {
            int f = t + 256 * it;
            int jj = f >> 4, q = f & 15;
            *(float4*)&Whl[jj * 68 + q * 4] = *(const float4*)&wh[(bN + j0 + jj) * 64 + q * 4];
        }
        // p tile: wave w covers rows r = w+4q, lane jl covers column j0+jl (coalesced adj read)
        float adst = ws[WS_ADST + bN + j0 + jl];
        #pragma unroll
        for (int q = 0; q < 16; ++q) {
            int r = w + 4 * q;
            float av = adj[(bN + i0 + r) * N_ + j0 + jl];
            float e = lrelu2(asl[r] + adst);
            float pv = av > 0.f ? __expf(e - Ml[r]) : 0.f;
            pl[r * 68 + jl] = pv;
        }
        __syncthreads();
        #pragma unroll
        for (int jq = 0; jq < 16; ++jq) {
            float4 pv[4], wv[4];
            #pragma unroll
            for (int ri = 0; ri < 4; ++ri) pv[ri] = *(float4*)&pl[(r0 + ri) * 68 + jq * 4];
            #pragma unroll
            for (int k = 0; k < 4; ++k) wv[k] = *(float4*)&Whl[(jq * 4 + k) * 68 + c0];
            #pragma unroll
            for (int ri = 0; ri < 4; ++ri) {
                #pragma unroll
                for (int k = 0; k < 4; ++k) {
                    float ps = f4get(pv[ri], k);
                    acc[ri][0] += ps * wv[k].x; acc[ri][1] += ps * wv[k].y;
                    acc[ri][2] += ps * wv[k].z; acc[ri][3] += ps * wv[k].w;
                }
                dpart[ri] += pv[ri].x + pv[ri].y + pv[ri].z + pv[ri].w;
            }
        }
        __syncthreads();
    }
    #pragma unroll
    for (int ri = 0; ri < 4; ++ri) {
        int row = i0 + r0 + ri;
        float inv = 1.f / dpart[ri];
        float4 o; float v;
        v = acc[ri][0] * inv; o.x = v > 0.f ? v : expm1f(v);
        v = acc[ri][1] * inv; o.y = v > 0.f ? v : expm1f(v);
        v = acc[ri][2] * inv; o.z = v > 0.f ? v : expm1f(v);
        v = acc[ri][3] * inv; o.w = v > 0.f ? v : expm1f(v);
        *(float4*)&ws[WS_XH + (bN + row) * 64 + c0] = o;
    }
}

// ---------------- K3: LSTM gates + cell update. 16 rows/block ----------------
__global__ __launch_bounds__(256) void k3_lstm(const float* __restrict__ x, const float* __restrict__ c,
                                               const float* __restrict__ h, const float* __restrict__ ws,
                                               float* __restrict__ out)
{
    __shared__ float Al[16 * 132];   // [row][k]: k<64 = h, k>=64 = x
    __shared__ float gl[16 * 260];   // gate pre-activations [row][256]
    int t = threadIdx.x;
    int base = blockIdx.x * 16;
    {
        int r = t >> 4, k0 = (t & 15) * 8;
        const float* src = (k0 < 64) ? &h[(base + r) * 64 + k0] : &x[(base + r) * 64 + (k0 - 64)];
        *(float4*)&Al[r * 132 + k0]     = *(const float4*)&src[0];
        *(float4*)&Al[r * 132 + k0 + 4] = *(const float4*)&src[4];
    }
    __syncthreads();
    int og = t & 63, rg = t >> 6;
    int o0 = og * 4;
    const float* WT = &ws[WS_WT];
    float acc[4][4] = {};
    #pragma unroll
    for (int k0 = 0; k0 < 128; k0 += 4) {
        float4 wv[4], av[4];
        #pragma unroll
        for (int kk = 0; kk < 4; ++kk) wv[kk] = *(const float4*)&WT[(k0 + kk) * 256 + o0];
        #pragma unroll
        for (int rr = 0; rr < 4; ++rr) av[rr] = *(float4*)&Al[(rg + 4 * rr) * 132 + k0];
        #pragma unroll
        for (int rr = 0; rr < 4; ++rr)
            #pragma unroll
            for (int kk = 0; kk < 4; ++kk) {
                float as = f4get(av[rr], kk);
                acc[rr][0] += as * wv[kk].x; acc[rr][1] += as * wv[kk].y;
                acc[rr][2] += as * wv[kk].z; acc[rr][3] += as * wv[kk].w;
            }
    }
    float4 bbv = *(const float4*)&ws[WS_BB + o0];
    #pragma unroll
    for (int rr = 0; rr < 4; ++rr) {
        int r = rg + 4 * rr;
        *(float4*)&gl[r * 260 + o0] = make_float4(acc[rr][0] + bbv.x, acc[rr][1] + bbv.y,
                                                  acc[rr][2] + bbv.z, acc[rr][3] + bbv.w);
    }
    __syncthreads();
    int u = t & 63, rq = t >> 6;
    #pragma unroll
    for (int pp = 0; pp < 4; ++pp) {
        int r = rq + 4 * pp;
        float gf = gl[r * 260 + u];
        float gi = gl[r * 260 + 64 + u];
        float go = gl[r * 260 + 128 + u];
        float gc = gl[r * 260 + 192 + u];
        float fg = 1.f / (1.f + __expf(-gf));
        float ig = 1.f / (1.f + __expf(-gi));
        float oo = 1.f / (1.f + __expf(-go));
        float ch = tanhf(gc);
        float cv = c[(base + r) * 64 + u];
        float ct = fg * cv + ig * ch;
        float ht = oo * fmaxf(ct, 0.f);
        out[OUTSZ + (base + r) * 64 + u] = ht;
        out[2 * OUTSZ + (base + r) * 64 + u] = ct;
    }
}

// ---------------- K5: output = relu([x_hidden | h_t] @ WoutT + bout). 64 rows/block ----------------
__global__ __launch_bounds__(256) void k5_out(const float* __restrict__ ws, const float* __restrict__ bout,
                                              float* __restrict__ out)
{
    __shared__ float Al[64 * 132];
    int t = threadIdx.x;
    int base = blockIdx.x * 64;
    const float* xh = &ws[WS_XH];
    const float* ht = &out[OUTSZ];
    #pragma unroll
    for (int it = 0; it < 8; ++it) {
        int f = t + 256 * it;
        int r = f >> 5, q = f & 31;
        int k0 = q * 4;
        float4 v;
        if (k0 < 64) v = *(const float4*)&xh[(base + r) * 64 + k0];
        else         v = *(const float4*)&ht[(base + r) * 64 + (k0 - 64)];
        *(float4*)&Al[r * 132 + k0] = v;
    }
    __syncthreads();
    int cg = t & 15, rgG = t >> 4;
    int c0 = cg * 4, r0 = rgG * 4;
    const float* WT = &ws[WS_WOT];
    float acc[4][4] = {};
    #pragma unroll
    for (int k0 = 0; k0 < 128; k0 += 4) {
        float4 wv[4], av[4];
        #pragma unroll
        for (int kk = 0; kk < 4; ++kk) wv[kk] = *(const float4*)&WT[(k0 + kk) * 64 + c0];
        #pragma unroll
        for (int ri = 0; ri < 4; ++ri) av[ri] = *(float4*)&Al[(r0 + ri) * 132 + k0];
        #pragma unroll
        for (int ri = 0; ri < 4; ++ri)
            #pragma unroll
            for (int kk = 0; kk < 4; ++kk) {
                float as = f4get(av[ri], kk);
                acc[ri][0] += as * wv[kk].x; acc[ri][1] += as * wv[kk].y;
                acc[ri][2] += as * wv[kk].z; acc[ri][3] += as * wv[kk].w;
            }
    }
    float4 bo = *(const float4*)&bout[c0];
    #pragma unroll
    for (int ri = 0; ri < 4; ++ri) {
        int row = base + r0 + ri;
        float4 o;
        o.x = fmaxf(acc[ri][0] + bo.x, 0.f);
        o.y = fmaxf(acc[ri][1] + bo.y, 0.f);
        o.z = fmaxf(acc[ri][2] + bo.z, 0.f);
        o.w = fmaxf(acc[ri][3] + bo.w, 0.f);
        *(float4*)&out[row * 64 + c0] = o;
    }
}

extern "C" void kernel_launch(void* const* d_in, const int* in_sizes, int n_in,
                              void* d_out, int out_size, void* d_ws, size_t ws_size,
                              hipStream_t stream)
{
    const float* x    = (const float*)d_in[0];
    const float* adj  = (const float*)d_in[1];
    const float* c    = (const float*)d_in[2];
    const float* h    = (const float*)d_in[3];
    const float* W    = (const float*)d_in[4];
    const float* a    = (const float*)d_in[5];
    const float* Wf   = (const float*)d_in[6];
    const float* bWf  = (const float*)d_in[7];
    const float* Wi   = (const float*)d_in[8];
    const float* bWi  = (const float*)d_in[9];
    const float* Wo   = (const float*)d_in[10];
    const float* bWo  = (const float*)d_in[11];
    const float* Wc   = (const float*)d_in[12];
    const float* bWc  = (const float*)d_in[13];
    const float* Uf   = (const float*)d_in[14];
    const float* bUf  = (const float*)d_in[15];
    const float* Ui   = (const float*)d_in[16];
    const float* bUi  = (const float*)d_in[17];
    const float* Uo   = (const float*)d_in[18];
    const float* bUo  = (const float*)d_in[19];
    const float* Uc   = (const float*)d_in[20];
    const float* bUc  = (const float*)d_in[21];
    const float* Wout = (const float*)d_in[22];
    const float* bout = (const float*)d_in[23];
    float* out = (float*)d_out;
    float* ws  = (float*)d_ws;
    float* wh  = out;   // Wh scratch lives in d_out segment 0; k5 overwrites it last

    k0_prep<<<161, 256, 0, stream>>>(Wf, Wi, Wo, Wc, Uf, Ui, Uo, Uc,
                                     bWf, bWi, bWo, bWc, bUf, bUi, bUo, bUc, Wout, ws);
    k1_wh<<<NT_ / 64, 256, 0, stream>>>(x, W, a, ws, wh);
    k1b_gmax<<<B_, 256, 0, stream>>>(ws);
    k3_lstm<<<NT_ / 16, 256, 0, stream>>>(x, c, h, ws, out);
    k2_att<<<NT_ / 64, 256, 0, stream>>>(adj, wh, ws);
    k5_out<<<NT_ / 64, 256, 0, stream>>>(ws, bout, out);
}

// Round 2
// 106.172 us; speedup vs baseline: 3.1188x; 3.1188x over previous
//
#include <hip/hip_runtime.h>
#include <math.h>

#define B_ 8
#define N_ 2048
#define NT_ (B_*N_)          // 16384 rows
#define OUTSZ (NT_*64)       // 1048576 elements per output tensor

// ---- workspace layout (float offsets) ----
#define WS_XH    0                       // x_hidden f32 [NT_][64]
#define WS_ASRC  (WS_XH + NT_*64)        // 1048576
#define WS_ADST  (WS_ASRC + NT_)
#define WS_GMAX  (WS_ADST + NT_)
#define WS_WT    (WS_GMAX + 32)          // [128][256] fused gate weights (transposed)
#define WS_BB    (WS_WT + 128*256)       // [256] combined gate bias
#define WS_WOT   (WS_BB + 256)           // [128][64] Wout transposed
#define WS_DPART (WS_WOT + 128*64)       // [js][NT_] partial softmax denominators
#define WS_PART  (WS_DPART + 4*NT_)      // [js][NT_][64] partial numerators
// fixed part (through WS_DPART start) = 1,122,592 floats = 4.49 MB (known-good size)
// WhT bf16 [B][64][N] lives in d_out[0 .. 524288 floats) -- dead until k5 overwrites.

typedef float f32x4 __attribute__((ext_vector_type(4)));
typedef __bf16 bf16x8 __attribute__((ext_vector_type(8)));
typedef __bf16 bf16x4 __attribute__((ext_vector_type(4)));

__device__ __forceinline__ float lrelu2(float x) { return x > 0.f ? x : 2.f * x; }
__device__ __forceinline__ float f4get(const float4& v, int k) { return k==0?v.x:(k==1?v.y:(k==2?v.z:v.w)); }

// ---------------- K0: weight prep (transpose gate weights into [k][256], WoutT) ----------------
__global__ void k0_prep(const float* Wf, const float* Wi, const float* Wo, const float* Wc,
                        const float* Uf, const float* Ui, const float* Uo, const float* Uc,
                        const float* bWf, const float* bWi, const float* bWo, const float* bWc,
                        const float* bUf, const float* bUi, const float* bUo, const float* bUc,
                        const float* Wout, float* ws)
{
    int idx = blockIdx.x * 256 + threadIdx.x;
    if (idx < 128 * 256) {
        int k = idx >> 8, o = idx & 255;
        int g = o >> 6, u = o & 63;
        const float* Wg = (g == 0) ? Wf : (g == 1) ? Wi : (g == 2) ? Wo : Wc;
        const float* Ug = (g == 0) ? Uf : (g == 1) ? Ui : (g == 2) ? Uo : Uc;
        ws[WS_WT + idx] = (k < 64) ? Wg[u * 64 + k] : Ug[u * 64 + (k - 64)];
    } else if (idx < 128 * 256 + 256) {
        int o = idx - 128 * 256;
        int g = o >> 6, u = o & 63;
        const float* bW = (g == 0) ? bWf : (g == 1) ? bWi : (g == 2) ? bWo : bWc;
        const float* bU = (g == 0) ? bUf : (g == 1) ? bUi : (g == 2) ? bUo : bUc;
        ws[WS_BB + o] = bW[u] + bU[u];
    } else if (idx < 128 * 256 + 256 + 128 * 64) {
        int j = idx - (128 * 256 + 256);
        int k = j >> 6, u = j & 63;
        ws[WS_WOT + j] = Wout[u * 128 + k];   // WoutT[k][u]
    }
}

// ---------------- K1: Wh = x@W -> WhT bf16 [b][h][j], a_src, a_dst ----------------
__global__ __launch_bounds__(256) void k1_wh(const float* __restrict__ x, const float* __restrict__ W,
                                             const float* __restrict__ a, float* __restrict__ ws,
                                             __bf16* __restrict__ whT)
{
    __shared__ float xl[64 * 68];
    __shared__ float Wl[64 * 68];
    int t = threadIdx.x;
    int i0 = blockIdx.x * 64;
    #pragma unroll
    for (int it = 0; it < 4; ++it) {
        int f = t + 256 * it;
        int r = f >> 4, q = f & 15;
        *(float4*)&xl[r * 68 + q * 4] = *(const float4*)&x[i0 * 64 + f * 4];
        *(float4*)&Wl[r * 68 + q * 4] = *(const float4*)&W[f * 4];
    }
    __syncthreads();
    int cg = t & 15, rg = t >> 4;
    int c0 = cg * 4, r0 = rg * 4;
    float acc[4][4] = {};
    #pragma unroll
    for (int d0 = 0; d0 < 64; d0 += 4) {
        float4 wv[4], xv[4];
        #pragma unroll
        for (int k = 0; k < 4; ++k) wv[k] = *(float4*)&Wl[(d0 + k) * 68 + c0];
        #pragma unroll
        for (int ri = 0; ri < 4; ++ri) xv[ri] = *(float4*)&xl[(r0 + ri) * 68 + d0];
        #pragma unroll
        for (int ri = 0; ri < 4; ++ri)
            #pragma unroll
            for (int k = 0; k < 4; ++k) {
                float xs = f4get(xv[ri], k);
                acc[ri][0] += xs * wv[k].x; acc[ri][1] += xs * wv[k].y;
                acc[ri][2] += xs * wv[k].z; acc[ri][3] += xs * wv[k].w;
            }
    }
    // transposed bf16 write: WhT[b][h=c0+cj][j=rowb0..+3]
    int b = i0 >> 11;
    int rowb0 = (i0 & 2047) + r0;
    #pragma unroll
    for (int cj = 0; cj < 4; ++cj) {
        bf16x4 v;
        v[0] = (__bf16)acc[0][cj]; v[1] = (__bf16)acc[1][cj];
        v[2] = (__bf16)acc[2][cj]; v[3] = (__bf16)acc[3][cj];
        *(bf16x4*)&whT[((size_t)(b * 64 + c0 + cj)) * N_ + rowb0] = v;
    }
    float4 a0 = *(const float4*)&a[c0];
    float4 a1 = *(const float4*)&a[64 + c0];
    #pragma unroll
    for (int ri = 0; ri < 4; ++ri) {
        int row = i0 + r0 + ri;
        float s0 = acc[ri][0]*a0.x + acc[ri][1]*a0.y + acc[ri][2]*a0.z + acc[ri][3]*a0.w;
        float s1 = acc[ri][0]*a1.x + acc[ri][1]*a1.y + acc[ri][2]*a1.z + acc[ri][3]*a1.w;
        #pragma unroll
        for (int m = 1; m < 16; m <<= 1) { s0 += __shfl_xor(s0, m, 64); s1 += __shfl_xor(s1, m, 64); }
        if (cg == 0) { ws[WS_ASRC + row] = s0; ws[WS_ADST + row] = s1; }
    }
}

// ---------------- K1b: per-batch max of a_dst ----------------
__global__ void k1b_gmax(float* ws)
{
    __shared__ float red[256];
    int b = blockIdx.x, t = threadIdx.x;
    float m = -3.0e38f;
    for (int j = t; j < N_; j += 256) m = fmaxf(m, ws[WS_ADST + b * N_ + j]);
    red[t] = m; __syncthreads();
    for (int s = 128; s > 0; s >>= 1) { if (t < s) red[t] = fmaxf(red[t], red[t + s]); __syncthreads(); }
    if (t == 0) ws[WS_GMAX + b] = red[0];
}

// ---------------- K2m: masked-softmax-weighted GEMM via MFMA, j-split ----------------
// 1 wave per block, 16 rows per wave, j range [js*jlen, +jlen). No LDS, no barriers.
// A-frag (p) generated in registers: lane -> (row=lane&15, kgroup=lane>>4), elems = 8 consecutive j.
// B-frag from WhT[b][h][j] global: lane -> (col=lane&15, same kgroup), 16B contiguous load.
// Same (group,elem)->k map on A and B => sum over k is correct for any HW-internal k-permutation.
__global__ __launch_bounds__(64) void k2m(const float* __restrict__ adj,
                                          const __bf16* __restrict__ whT,
                                          float* __restrict__ ws, int js_count)
{
    int lane = threadIdx.x;
    int r = lane & 15, g = lane >> 4;
    int blk = blockIdx.x;
    int rb = blk / js_count;
    int js = blk - rb * js_count;
    int row0 = rb * 16;
    int b = row0 >> 11;
    int jlen = N_ / js_count;
    int jbeg = js * jlen;

    float as = ws[WS_ASRC + row0 + r];
    float M = lrelu2(as + ws[WS_GMAX + b]);
    const float* adjrow = &adj[(size_t)(row0 + r) * N_];
    const float* adstp = &ws[WS_ADST + b * N_];
    const __bf16* bb = &whT[((size_t)(b * 64 + r)) * N_];

    f32x4 acc0 = {0.f,0.f,0.f,0.f}, acc1 = {0.f,0.f,0.f,0.f};
    f32x4 acc2 = {0.f,0.f,0.f,0.f}, acc3 = {0.f,0.f,0.f,0.f};
    float dsum = 0.f;

    for (int j0 = jbeg; j0 < jbeg + jlen; j0 += 32) {
        int jk = j0 + g * 8;
        float4 av0 = *(const float4*)&adjrow[jk];
        float4 av1 = *(const float4*)&adjrow[jk + 4];
        float4 d0  = *(const float4*)&adstp[jk];
        float4 d1  = *(const float4*)&adstp[jk + 4];
        float pvv[8];
        #pragma unroll
        for (int e = 0; e < 8; ++e) {
            float a_ = f4get(e < 4 ? av0 : av1, e & 3);
            float dd = f4get(e < 4 ? d0  : d1,  e & 3);
            float s = as + dd;
            float ee = fminf(s, s + s);          // leakyrelu slope 2
            float p_ = (a_ > 0.f) ? __expf(ee - M) : 0.f;
            pvv[e] = p_;
        }
        float ds_ = 0.f;
        #pragma unroll
        for (int e = 0; e < 8; ++e) ds_ += pvv[e];
        dsum += ds_;
        bf16x8 af;
        #pragma unroll
        for (int e = 0; e < 8; ++e) af[e] = (__bf16)pvv[e];
        bf16x8 b0 = *(const bf16x8*)&bb[jk];
        bf16x8 b1 = *(const bf16x8*)&bb[16 * N_ + jk];
        bf16x8 b2 = *(const bf16x8*)&bb[32 * N_ + jk];
        bf16x8 b3 = *(const bf16x8*)&bb[48 * N_ + jk];
        acc0 = __builtin_amdgcn_mfma_f32_16x16x32_bf16(af, b0, acc0, 0, 0, 0);
        acc1 = __builtin_amdgcn_mfma_f32_16x16x32_bf16(af, b1, acc1, 0, 0, 0);
        acc2 = __builtin_amdgcn_mfma_f32_16x16x32_bf16(af, b2, acc2, 0, 0, 0);
        acc3 = __builtin_amdgcn_mfma_f32_16x16x32_bf16(af, b3, acc3, 0, 0, 0);
    }
    // reduce denominator across the 4 k-groups (lanes r, r+16, r+32, r+48)
    dsum += __shfl_xor(dsum, 16, 64);
    dsum += __shfl_xor(dsum, 32, 64);

    if (js_count == 1) {
        // direct finalize: need denominator for C-layout rows g*4+i
        float invr[4];
        #pragma unroll
        for (int i = 0; i < 4; ++i) invr[i] = 1.f / __shfl(dsum, g * 4 + i, 64);
        auto fin = [&](f32x4 acc_, int n) {
            #pragma unroll
            for (int i = 0; i < 4; ++i) {
                int row = row0 + g * 4 + i;
                float v = acc_[i] * invr[i];
                v = v > 0.f ? v : expm1f(v);
                ws[WS_XH + (size_t)row * 64 + n * 16 + r] = v;
            }
        };
        fin(acc0, 0); fin(acc1, 1); fin(acc2, 2); fin(acc3, 3);
    } else {
        float* part = &ws[WS_PART + (size_t)js * (NT_ * 64)];
        auto st = [&](f32x4 acc_, int n) {
            #pragma unroll
            for (int i = 0; i < 4; ++i) {
                int row = row0 + g * 4 + i;
                part[(size_t)row * 64 + n * 16 + r] = acc_[i];
            }
        };
        st(acc0, 0); st(acc1, 1); st(acc2, 2); st(acc3, 3);
        if (g == 0) ws[WS_DPART + js * NT_ + row0 + r] = dsum;
    }
}

// ---------------- K2c: combine j-split partials, divide, ELU ----------------
__global__ __launch_bounds__(256) void k2c(float* __restrict__ ws, int js_count)
{
    int idx = blockIdx.x * 256 + threadIdx.x;    // float4 units, NT_*16 total
    int row = idx >> 4;
    float4 s = make_float4(0.f, 0.f, 0.f, 0.f);
    float d = 0.f;
    for (int js = 0; js < js_count; ++js) {
        float4 p = *(const float4*)&ws[WS_PART + (size_t)js * (NT_ * 64) + (size_t)idx * 4];
        s.x += p.x; s.y += p.y; s.z += p.z; s.w += p.w;
        d += ws[WS_DPART + js * NT_ + row];
    }
    float inv = 1.f / d;
    float4 o;
    o.x = s.x * inv; o.x = o.x > 0.f ? o.x : expm1f(o.x);
    o.y = s.y * inv; o.y = o.y > 0.f ? o.y : expm1f(o.y);
    o.z = s.z * inv; o.z = o.z > 0.f ? o.z : expm1f(o.z);
    o.w = s.w * inv; o.w = o.w > 0.f ? o.w : expm1f(o.w);
    *(float4*)&ws[WS_XH + (size_t)idx * 4] = o;
}

// ---------------- K3: LSTM gates + cell update. 16 rows/block ----------------
__global__ __launch_bounds__(256) void k3_lstm(const float* __restrict__ x, const float* __restrict__ c,
                                               const float* __restrict__ h, const float* __restrict__ ws,
                                               float* __restrict__ out)
{
    __shared__ float Al[16 * 132];   // [row][k]: k<64 = h, k>=64 = x
    __shared__ float gl[16 * 260];   // gate pre-activations [row][256]
    int t = threadIdx.x;
    int base = blockIdx.x * 16;
    {
        int r = t >> 4, k0 = (t & 15) * 8;
        const float* src = (k0 < 64) ? &h[(base + r) * 64 + k0] : &x[(base + r) * 64 + (k0 - 64)];
        *(float4*)&Al[r * 132 + k0]     = *(const float4*)&src[0];
        *(float4*)&Al[r * 132 + k0 + 4] = *(const float4*)&src[4];
    }
    __syncthreads();
    int og = t & 63, rg = t >> 6;
    int o0 = og * 4;
    const float* WT = &ws[WS_WT];
    float acc[4][4] = {};
    #pragma unroll
    for (int k0 = 0; k0 < 128; k0 += 4) {
        float4 wv[4], av[4];
        #pragma unroll
        for (int kk = 0; kk < 4; ++kk) wv[kk] = *(const float4*)&WT[(k0 + kk) * 256 + o0];
        #pragma unroll
        for (int rr = 0; rr < 4; ++rr) av[rr] = *(float4*)&Al[(rg + 4 * rr) * 132 + k0];
        #pragma unroll
        for (int rr = 0; rr < 4; ++rr)
            #pragma unroll
            for (int kk = 0; kk < 4; ++kk) {
                float as = f4get(av[rr], kk);
                acc[rr][0] += as * wv[kk].x; acc[rr][1] += as * wv[kk].y;
                acc[rr][2] += as * wv[kk].z; acc[rr][3] += as * wv[kk].w;
            }
    }
    float4 bbv = *(const float4*)&ws[WS_BB + o0];
    #pragma unroll
    for (int rr = 0; rr < 4; ++rr) {
        int r = rg + 4 * rr;
        *(float4*)&gl[r * 260 + o0] = make_float4(acc[rr][0] + bbv.x, acc[rr][1] + bbv.y,
                                                  acc[rr][2] + bbv.z, acc[rr][3] + bbv.w);
    }
    __syncthreads();
    int u = t & 63, rq = t >> 6;
    #pragma unroll
    for (int pp = 0; pp < 4; ++pp) {
        int r = rq + 4 * pp;
        float gf = gl[r * 260 + u];
        float gi = gl[r * 260 + 64 + u];
        float go = gl[r * 260 + 128 + u];
        float gc = gl[r * 260 + 192 + u];
        float fg = 1.f / (1.f + __expf(-gf));
        float ig = 1.f / (1.f + __expf(-gi));
        float oo = 1.f / (1.f + __expf(-go));
        float ch = tanhf(gc);
        float cv = c[(base + r) * 64 + u];
        float ct = fg * cv + ig * ch;
        float ht = oo * fmaxf(ct, 0.f);
        out[OUTSZ + (base + r) * 64 + u] = ht;
        out[2 * OUTSZ + (base + r) * 64 + u] = ct;
    }
}

// ---------------- K5: output = relu([x_hidden | h_t] @ WoutT + bout). 64 rows/block ----------------
__global__ __launch_bounds__(256) void k5_out(const float* __restrict__ ws, const float* __restrict__ bout,
                                              float* __restrict__ out)
{
    __shared__ float Al[64 * 132];
    int t = threadIdx.x;
    int base = blockIdx.x * 64;
    const float* xh = &ws[WS_XH];
    const float* ht = &out[OUTSZ];
    #pragma unroll
    for (int it = 0; it < 8; ++it) {
        int f = t + 256 * it;
        int r = f >> 5, q = f & 31;
        int k0 = q * 4;
        float4 v;
        if (k0 < 64) v = *(const float4*)&xh[(base + r) * 64 + k0];
        else         v = *(const float4*)&ht[(base + r) * 64 + (k0 - 64)];
        *(float4*)&Al[r * 132 + k0] = v;
    }
    __syncthreads();
    int cg = t & 15, rgG = t >> 4;
    int c0 = cg * 4, r0 = rgG * 4;
    const float* WT = &ws[WS_WOT];
    float acc[4][4] = {};
    #pragma unroll
    for (int k0 = 0; k0 < 128; k0 += 4) {
        float4 wv[4], av[4];
        #pragma unroll
        for (int kk = 0; kk < 4; ++kk) wv[kk] = *(const float4*)&WT[(k0 + kk) * 64 + c0];
        #pragma unroll
        for (int ri = 0; ri < 4; ++ri) av[ri] = *(float4*)&Al[(r0 + ri) * 132 + k0];
        #pragma unroll
        for (int ri = 0; ri < 4; ++ri)
            #pragma unroll
            for (int kk = 0; kk < 4; ++kk) {
                float as = f4get(av[ri], kk);
                acc[ri][0] += as * wv[kk].x; acc[ri][1] += as * wv[kk].y;
                acc[ri][2] += as * wv[kk].z; acc[ri][3] += as * wv[kk].w;
            }
    }
    float4 bo = *(const float4*)&bout[c0];
    #pragma unroll
    for (int ri = 0; ri < 4; ++ri) {
        int row = base + r0 + ri;
        float4 o;
        o.x = fmaxf(acc[ri][0] + bo.x, 0.f);
        o.y = fmaxf(acc[ri][1] + bo.y, 0.f);
        o.z = fmaxf(acc[ri][2] + bo.z, 0.f);
        o.w = fmaxf(acc[ri][3] + bo.w, 0.f);
        *(float4*)&out[row * 64 + c0] = o;
    }
}

extern "C" void kernel_launch(void* const* d_in, const int* in_sizes, int n_in,
                              void* d_out, int out_size, void* d_ws, size_t ws_size,
                              hipStream_t stream)
{
    const float* x    = (const float*)d_in[0];
    const float* adj  = (const float*)d_in[1];
    const float* c    = (const float*)d_in[2];
    const float* h    = (const float*)d_in[3];
    const float* W    = (const float*)d_in[4];
    const float* a    = (const float*)d_in[5];
    const float* Wf   = (const float*)d_in[6];
    const float* bWf  = (const float*)d_in[7];
    const float* Wi   = (const float*)d_in[8];
    const float* bWi  = (const float*)d_in[9];
    const float* Wo   = (const float*)d_in[10];
    const float* bWo  = (const float*)d_in[11];
    const float* Wc   = (const float*)d_in[12];
    const float* bWc  = (const float*)d_in[13];
    const float* Uf   = (const float*)d_in[14];
    const float* bUf  = (const float*)d_in[15];
    const float* Ui   = (const float*)d_in[16];
    const float* bUi  = (const float*)d_in[17];
    const float* Uo   = (const float*)d_in[18];
    const float* bUo  = (const float*)d_in[19];
    const float* Uc   = (const float*)d_in[20];
    const float* bUc  = (const float*)d_in[21];
    const float* Wout = (const float*)d_in[22];
    const float* bout = (const float*)d_in[23];
    float* out = (float*)d_out;
    float* ws  = (float*)d_ws;
    __bf16* whT = (__bf16*)out;   // WhT bf16 scratch in d_out segment 0; k5 overwrites last

    // pick j-split that fits the workspace (js=1 uses only the known-good 4.5 MB layout)
    size_t wsf = ws_size / sizeof(float);
    int js = 1;
    if ((size_t)WS_PART + 4ull * NT_ * 64 <= wsf) js = 4;
    else if ((size_t)WS_PART + 2ull * NT_ * 64 <= wsf) js = 2;

    k0_prep<<<161, 256, 0, stream>>>(Wf, Wi, Wo, Wc, Uf, Ui, Uo, Uc,
                                     bWf, bWi, bWo, bWc, bUf, bUi, bUo, bUc, Wout, ws);
    k1_wh<<<NT_ / 64, 256, 0, stream>>>(x, W, a, ws, whT);
    k1b_gmax<<<B_, 256, 0, stream>>>(ws);
    k3_lstm<<<NT_ / 16, 256, 0, stream>>>(x, c, h, ws, out);
    k2m<<<(NT_ / 16) * js, 64, 0, stream>>>(adj, whT, ws, js);
    if (js > 1) k2c<<<NT_ * 16 / 256, 256, 0, stream>>>(ws, js);
    k5_out<<<NT_ / 64, 256, 0, stream>>>(ws, bout, out);
}